// Round 1
// baseline (707.449 us; speedup 1.0000x reference)
//
#include <hip/hip_runtime.h>

// ---------------- constants ----------------
#define HIDDEN 2048
#define NHEADS 16
#define NKV 4
#define HEAD_DIM 128
#define BB 2
#define TT 2048
#define MROWS (BB * TT)          // 4096
#define NQKV (NHEADS * HEAD_DIM + 2 * NKV * HEAD_DIM)  // 3072

typedef __attribute__((ext_vector_type(8))) short short8;
typedef __attribute__((ext_vector_type(4))) float f32x4;

__device__ __forceinline__ unsigned short f2bf(float f) {
    unsigned int u = __float_as_uint(f);
    unsigned int r = u + 0x7fffu + ((u >> 16) & 1u);
    return (unsigned short)(r >> 16);
}
__device__ __forceinline__ float b2f(unsigned short h) {
    return __uint_as_float(((unsigned int)h) << 16);
}

__device__ __forceinline__ void store_out(float* p, float v) { *p = v; }
__device__ __forceinline__ void store_out(unsigned short* p, float v) { *p = f2bf(v); }

// ---------------- cast x to bf16 ----------------
__global__ void cast_x_kernel(const float* __restrict__ x, unsigned short* __restrict__ xb) {
    int i = blockIdx.x * 256 + threadIdx.x;   // one float4 per thread
    float4 v = ((const float4*)x)[i];
    ushort4 o;
    o.x = f2bf(v.x); o.y = f2bf(v.y); o.z = f2bf(v.z); o.w = f2bf(v.w);
    ((ushort4*)xb)[i] = o;
}

// ---------------- pack wq|wk|wv -> WqkvT (N=3072 rows, K=2048 cols), bf16 ----------------
__global__ void pack_wqkvT_kernel(const float* __restrict__ wq, const float* __restrict__ wk,
                                  const float* __restrict__ wv, unsigned short* __restrict__ out) {
    __shared__ float tile[32][33];
    int n0 = blockIdx.x * 32, k0 = blockIdx.y * 32;
    int tx = threadIdx.x, ty = threadIdx.y;
#pragma unroll
    for (int i = 0; i < 32; i += 8) {
        int k = k0 + ty + i;
        int n = n0 + tx;
        float v;
        if (n < 2048)      v = wq[(size_t)k * 2048 + n];
        else if (n < 2560) v = wk[(size_t)k * 512 + (n - 2048)];
        else               v = wv[(size_t)k * 512 + (n - 2560)];
        tile[ty + i][tx] = v;
    }
    __syncthreads();
#pragma unroll
    for (int i = 0; i < 32; i += 8) {
        int n = n0 + ty + i;
        int k = k0 + tx;
        out[(size_t)n * HIDDEN + k] = f2bf(tile[tx][ty + i]);
    }
}

// ---------------- transpose wo -> WoT (N=2048 rows, K=2048 cols), bf16 ----------------
__global__ void pack_woT_kernel(const float* __restrict__ wo, unsigned short* __restrict__ out) {
    __shared__ float tile[32][33];
    int n0 = blockIdx.x * 32, k0 = blockIdx.y * 32;
    int tx = threadIdx.x, ty = threadIdx.y;
#pragma unroll
    for (int i = 0; i < 32; i += 8)
        tile[ty + i][tx] = wo[(size_t)(k0 + ty + i) * HIDDEN + n0 + tx];
    __syncthreads();
#pragma unroll
    for (int i = 0; i < 32; i += 8)
        out[(size_t)(n0 + ty + i) * HIDDEN + k0 + tx] = f2bf(tile[tx][ty + i]);
}

// ---------------- GEMM: C(MxN) = A(MxK bf16) @ Bt(NxK bf16)^T ----------------
// 128x128 tile per block (256 thr = 4 waves, each wave 64x64 = 4x4 mfma tiles), BK=32.
template <typename OutT>
__global__ __launch_bounds__(256) void gemm_bt_kernel(const unsigned short* __restrict__ A,
                                                      const unsigned short* __restrict__ Bt,
                                                      OutT* __restrict__ C,
                                                      int M, int N, int K) {
    // padded stride 40 halfwords (80 B = 20 words): rows 2-way bank alias only (free)
    __shared__ __align__(16) unsigned short sA[128 * 40];
    __shared__ __align__(16) unsigned short sB[128 * 40];
    const int tid = threadIdx.x;
    const int lane = tid & 63, w = tid >> 6;
    const int quad = lane >> 4, l15 = lane & 15;
    const int wr = w >> 1, wc = w & 1;
    const int m0 = blockIdx.y * 128, n0 = blockIdx.x * 128;

    f32x4 acc[4][4];
    const f32x4 z4 = {0.f, 0.f, 0.f, 0.f};
#pragma unroll
    for (int mi = 0; mi < 4; ++mi)
#pragma unroll
        for (int ni = 0; ni < 4; ++ni) acc[mi][ni] = z4;

    for (int kk = 0; kk < K; kk += 32) {
        __syncthreads();
#pragma unroll
        for (int it = 0; it < 2; ++it) {
            int c = tid + 256 * it;
            int row = c >> 2, col8 = c & 3;   // 4 chunks of 8 bf16 per 32-wide row
            uint4 va = *(const uint4*)(A + (size_t)(m0 + row) * K + kk + col8 * 8);
            *(uint4*)(&sA[row * 40 + col8 * 8]) = va;
            uint4 vb = *(const uint4*)(Bt + (size_t)(n0 + row) * K + kk + col8 * 8);
            *(uint4*)(&sB[row * 40 + col8 * 8]) = vb;
        }
        __syncthreads();
        short8 af[4], bf[4];
#pragma unroll
        for (int i = 0; i < 4; ++i) {
            af[i] = *(const short8*)(&sA[(wr * 64 + i * 16 + l15) * 40 + quad * 8]);
            bf[i] = *(const short8*)(&sB[(wc * 64 + i * 16 + l15) * 40 + quad * 8]);
        }
#pragma unroll
        for (int mi = 0; mi < 4; ++mi)
#pragma unroll
            for (int ni = 0; ni < 4; ++ni)
                acc[mi][ni] = __builtin_amdgcn_mfma_f32_16x16x32_bf16(af[mi], bf[ni], acc[mi][ni], 0, 0, 0);
    }
#pragma unroll
    for (int mi = 0; mi < 4; ++mi)
#pragma unroll
        for (int ni = 0; ni < 4; ++ni)
#pragma unroll
            for (int r = 0; r < 4; ++r) {
                int gr = m0 + wr * 64 + mi * 16 + quad * 4 + r;
                int gc = n0 + wc * 64 + ni * 16 + l15;
                store_out(&C[(size_t)gr * N + gc], acc[mi][ni][r]);
            }
}

// ---------------- RoPE + reshape: qkv(M x 3072 bf16) -> Q(B,NH,T,128) K,V(B,NKV,T,128) bf16 ----------------
#define QP (MROWS * NHEADS * 64)  // 4194304
#define KP (MROWS * NKV * 64)     // 1048576
__global__ void rope_kernel(const unsigned short* __restrict__ qkv,
                            const float* __restrict__ cosb, const float* __restrict__ sinb,
                            unsigned short* __restrict__ Q, unsigned short* __restrict__ K,
                            unsigned short* __restrict__ V) {
    int tid = blockIdx.x * 256 + threadIdx.x;
    if (tid < QP) {
        int d = tid & 63;
        int h = (tid >> 6) & 15;
        int row = tid >> 10;
        int t = row & (TT - 1), b = row >> 11;
        float x1 = b2f(qkv[(size_t)row * NQKV + h * 128 + d]);
        float x2 = b2f(qkv[(size_t)row * NQKV + h * 128 + d + 64]);
        float c = cosb[t * 64 + d], s = sinb[t * 64 + d];
        unsigned short* dst = Q + ((size_t)(b * NHEADS + h) * TT + t) * 128 + d;
        dst[0]  = f2bf(x1 * c - x2 * s);
        dst[64] = f2bf(x2 * c + x1 * s);
    } else if (tid < QP + KP) {
        int p = tid - QP;
        int d = p & 63;
        int kh = (p >> 6) & 3;
        int row = p >> 8;
        int t = row & (TT - 1), b = row >> 11;
        float x1 = b2f(qkv[(size_t)row * NQKV + 2048 + kh * 128 + d]);
        float x2 = b2f(qkv[(size_t)row * NQKV + 2048 + kh * 128 + d + 64]);
        float c = cosb[t * 64 + d], s = sinb[t * 64 + d];
        unsigned short* dst = K + ((size_t)(b * NKV + kh) * TT + t) * 128 + d;
        dst[0]  = f2bf(x1 * c - x2 * s);
        dst[64] = f2bf(x2 * c + x1 * s);
    } else {
        int p = tid - QP - KP;
        int d = p & 63;
        int kh = (p >> 6) & 3;
        int row = p >> 8;
        int t = row & (TT - 1), b = row >> 11;
        unsigned short* dst = V + ((size_t)(b * NKV + kh) * TT + t) * 128 + d;
        dst[0]  = qkv[(size_t)row * NQKV + 2560 + kh * 128 + d];
        dst[64] = qkv[(size_t)row * NQKV + 2560 + kh * 128 + d + 64];
    }
}

// ---------------- flash attention: 64 q-rows/block (16/wave), 32-wide kv tiles ----------------
__global__ __launch_bounds__(256) void flash_kernel(const unsigned short* __restrict__ Qb,
                                                    const unsigned short* __restrict__ Kb,
                                                    const unsigned short* __restrict__ Vb,
                                                    unsigned short* __restrict__ Ob) {
    __shared__ __align__(16) unsigned short sK[32 * 136];   // [kv][d], stride 136 (pad)
    __shared__ __align__(16) unsigned short sVt[128 * 40];  // [d][kv], stride 40 (pad)
    __shared__ __align__(16) unsigned short sP[4][16 * 40]; // per-wave P, stride 40

    const int tid = threadIdx.x;
    const int w = tid >> 6, lane = tid & 63;
    const int quad = lane >> 4, l15 = lane & 15;
    const int b = blockIdx.z, h = blockIdx.y;
    const int q0 = blockIdx.x * 64;
    const int kvh = h >> 2;   // GROUPS = 4
    const unsigned short* Qh = Qb + (size_t)(b * NHEADS + h) * TT * 128;
    const unsigned short* Kh = Kb + (size_t)(b * NKV + kvh) * TT * 128;
    const unsigned short* Vh = Vb + (size_t)(b * NKV + kvh) * TT * 128;

    // Q fragments (A-operand): A[m=l15][d = quad*8 + j + 32*dk]
    short8 aq[4];
    const int qload = q0 + w * 16 + l15;
#pragma unroll
    for (int dk = 0; dk < 4; ++dk)
        aq[dk] = *(const short8*)(Qh + (size_t)qload * 128 + dk * 32 + quad * 8);

    f32x4 accO[8];
    const f32x4 z4 = {0.f, 0.f, 0.f, 0.f};
#pragma unroll
    for (int nb = 0; nb < 8; ++nb) accO[nb] = z4;
    float m_i[4], l_i[4];
#pragma unroll
    for (int r = 0; r < 4; ++r) { m_i[r] = -1e30f; l_i[r] = 0.f; }

    const int kv_end = q0 + 64;
    const int qmax_wave = q0 + w * 16 + 15;
    const float scale = 0.08838834764831845f;  // 1/sqrt(128)

    for (int kv0 = 0; kv0 < kv_end; kv0 += 32) {
        __syncthreads();
#pragma unroll
        for (int it = 0; it < 2; ++it) {
            int c = tid + 256 * it;
            int row = c >> 4, ch = c & 15;
            uint4 kvec = *(const uint4*)(Kh + (size_t)(kv0 + row) * 128 + ch * 8);
            *(uint4*)(&sK[row * 136 + ch * 8]) = kvec;
            union { uint4 v; unsigned short u[8]; } vv;
            vv.v = *(const uint4*)(Vh + (size_t)(kv0 + row) * 128 + ch * 8);
#pragma unroll
            for (int j = 0; j < 8; ++j)
                sVt[(ch * 8 + j) * 40 + row] = vv.u[j];
        }
        __syncthreads();

        if (kv0 <= qmax_wave) {   // wave-uniform
            float p[2][4];
            // S = Q K^T for two 16-wide column halves
#pragma unroll
            for (int nh = 0; nh < 2; ++nh) {
                f32x4 sacc = z4;
#pragma unroll
                for (int dk = 0; dk < 4; ++dk) {
                    short8 bk = *(const short8*)(&sK[(nh * 16 + l15) * 136 + dk * 32 + quad * 8]);
                    sacc = __builtin_amdgcn_mfma_f32_16x16x32_bf16(aq[dk], bk, sacc, 0, 0, 0);
                }
                int col = kv0 + nh * 16 + l15;
#pragma unroll
                for (int r = 0; r < 4; ++r) {
                    int qr = q0 + w * 16 + quad * 4 + r;
                    float s = sacc[r] * scale;
                    p[nh][r] = (col <= qr) ? s : -1e30f;
                }
            }
            // online softmax per row (16-lane column groups)
#pragma unroll
            for (int r = 0; r < 4; ++r) {
                float mx = fmaxf(p[0][r], p[1][r]);
#pragma unroll
                for (int off = 1; off < 16; off <<= 1) mx = fmaxf(mx, __shfl_xor(mx, off, 64));
                float mnew = fmaxf(m_i[r], mx);
                float alpha = __expf(m_i[r] - mnew);
                float p0 = __expf(p[0][r] - mnew);
                float p1 = __expf(p[1][r] - mnew);
                p[0][r] = p0; p[1][r] = p1;
                float rs = p0 + p1;
#pragma unroll
                for (int off = 1; off < 16; off <<= 1) rs += __shfl_xor(rs, off, 64);
                l_i[r] = l_i[r] * alpha + rs;
                m_i[r] = mnew;
#pragma unroll
                for (int nb = 0; nb < 8; ++nb) accO[nb][r] *= alpha;
            }
            // P: C-layout -> A-layout via per-wave LDS round trip
            unsigned short* sPw = &sP[w][0];
#pragma unroll
            for (int nh = 0; nh < 2; ++nh)
#pragma unroll
                for (int r = 0; r < 4; ++r)
                    sPw[(quad * 4 + r) * 40 + nh * 16 + l15] = f2bf(p[nh][r]);
            __asm__ volatile("s_waitcnt lgkmcnt(0)" ::: "memory");
            short8 ap = *(const short8*)(&sPw[l15 * 40 + quad * 8]);
            // O += P @ V
#pragma unroll
            for (int nb = 0; nb < 8; ++nb) {
                short8 bv = *(const short8*)(&sVt[(nb * 16 + l15) * 40 + quad * 8]);
                accO[nb] = __builtin_amdgcn_mfma_f32_16x16x32_bf16(ap, bv, accO[nb], 0, 0, 0);
            }
        }
    }
    // epilogue: normalize and store (B*T rows, NH*HD cols)
#pragma unroll
    for (int r = 0; r < 4; ++r) {
        float inv = 1.0f / l_i[r];
        int qr = q0 + w * 16 + quad * 4 + r;
        size_t rowbase = ((size_t)b * TT + qr) * (NHEADS * HEAD_DIM) + h * 128;
#pragma unroll
        for (int nb = 0; nb < 8; ++nb)
            Ob[rowbase + nb * 16 + l15] = f2bf(accO[nb][r] * inv);
    }
}

// ---------------- launch ----------------
extern "C" void kernel_launch(void* const* d_in, const int* in_sizes, int n_in,
                              void* d_out, int out_size, void* d_ws, size_t ws_size,
                              hipStream_t stream) {
    const float* x    = (const float*)d_in[0];
    const float* cosb = (const float*)d_in[1];
    const float* sinb = (const float*)d_in[2];
    const float* wq   = (const float*)d_in[3];
    const float* wk   = (const float*)d_in[4];
    const float* wv   = (const float*)d_in[5];
    const float* wo   = (const float*)d_in[6];
    float* out = (float*)d_out;

    char* ws = (char*)d_ws;
    unsigned short* xb    = (unsigned short*)(ws);                       // 16 MB
    unsigned short* wqkvT = (unsigned short*)(ws + 16777216);            // 12 MB
    unsigned short* woT   = (unsigned short*)(ws + 29360128);            // 8 MB
    unsigned short* qkv   = (unsigned short*)(ws + 37748736);            // 24 MB (bf16 4096x3072)
    unsigned short* Qbuf  = (unsigned short*)(ws + 62914560);            // 16 MB
    unsigned short* Kbuf  = (unsigned short*)(ws + 79691776);            // 4 MB
    unsigned short* Vbuf  = (unsigned short*)(ws + 83886080);            // 4 MB
    unsigned short* attn  = (unsigned short*)(ws + 88080384);            // 16 MB -> total 100 MB

    cast_x_kernel<<<(MROWS * HIDDEN) / 4 / 256, 256, 0, stream>>>(x, xb);
    pack_wqkvT_kernel<<<dim3(NQKV / 32, HIDDEN / 32), dim3(32, 8), 0, stream>>>(wq, wk, wv, wqkvT);
    pack_woT_kernel<<<dim3(HIDDEN / 32, HIDDEN / 32), dim3(32, 8), 0, stream>>>(wo, woT);

    gemm_bt_kernel<unsigned short><<<dim3(NQKV / 128, MROWS / 128), 256, 0, stream>>>(
        xb, wqkvT, qkv, MROWS, NQKV, HIDDEN);

    rope_kernel<<<(QP + 2 * KP) / 256, 256, 0, stream>>>(qkv, cosb, sinb, Qbuf, Kbuf, Vbuf);

    flash_kernel<<<dim3(TT / 64, NHEADS, BB), 256, 0, stream>>>(Qbuf, Kbuf, Vbuf, attn);

    gemm_bt_kernel<float><<<dim3(HIDDEN / 128, MROWS / 128), 256, 0, stream>>>(
        attn, woT, out, MROWS, HIDDEN, HIDDEN);
}

// Round 3
// 549.973 us; speedup vs baseline: 1.2863x; 1.2863x over previous
//
#include <hip/hip_runtime.h>

// ---------------- constants ----------------
#define HIDDEN 2048
#define NHEADS 16
#define NKV 4
#define HEAD_DIM 128
#define BB 2
#define TT 2048
#define MROWS (BB * TT)          // 4096
#define NQKV (NHEADS * HEAD_DIM + 2 * NKV * HEAD_DIM)  // 3072

typedef __attribute__((ext_vector_type(8))) short short8;
typedef __attribute__((ext_vector_type(4))) float f32x4;

__device__ __forceinline__ unsigned short f2bf(float f) {
    unsigned int u = __float_as_uint(f);
    unsigned int r = u + 0x7fffu + ((u >> 16) & 1u);
    return (unsigned short)(r >> 16);
}
__device__ __forceinline__ float b2f(unsigned short h) {
    return __uint_as_float(((unsigned int)h) << 16);
}

__device__ __forceinline__ void store_out(float* p, float v) { *p = v; }
__device__ __forceinline__ void store_out(unsigned short* p, float v) { *p = f2bf(v); }

// async global->LDS, 16B per lane; lds dest = wave-uniform base + lane*16
__device__ __forceinline__ void load_lds_16(const void* g, void* l) {
    __builtin_amdgcn_global_load_lds((const __attribute__((address_space(1))) unsigned int*)g,
                                     (__attribute__((address_space(3))) unsigned int*)l,
                                     16, 0, 0);
}

// ---------------- cast x to bf16 ----------------
__global__ void cast_x_kernel(const float* __restrict__ x, unsigned short* __restrict__ xb) {
    int i = blockIdx.x * 256 + threadIdx.x;
    float4 v = ((const float4*)x)[i];
    ushort4 o;
    o.x = f2bf(v.x); o.y = f2bf(v.y); o.z = f2bf(v.z); o.w = f2bf(v.w);
    ((ushort4*)xb)[i] = o;
}

// ---------------- pack wq|wk|wv -> WqkvT (N=3072 rows, K=2048 cols), bf16 ----------------
__global__ void pack_wqkvT_kernel(const float* __restrict__ wq, const float* __restrict__ wk,
                                  const float* __restrict__ wv, unsigned short* __restrict__ out) {
    __shared__ float tile[32][33];
    int n0 = blockIdx.x * 32, k0 = blockIdx.y * 32;
    int tx = threadIdx.x, ty = threadIdx.y;
#pragma unroll
    for (int i = 0; i < 32; i += 8) {
        int k = k0 + ty + i;
        int n = n0 + tx;
        float v;
        if (n < 2048)      v = wq[(size_t)k * 2048 + n];
        else if (n < 2560) v = wk[(size_t)k * 512 + (n - 2048)];
        else               v = wv[(size_t)k * 512 + (n - 2560)];
        tile[ty + i][tx] = v;
    }
    __syncthreads();
#pragma unroll
    for (int i = 0; i < 32; i += 8) {
        int n = n0 + ty + i;
        int k = k0 + tx;
        out[(size_t)n * HIDDEN + k] = f2bf(tile[tx][ty + i]);
    }
}

// ---------------- transpose wo -> WoT (N=2048 rows, K=2048 cols), bf16 ----------------
__global__ void pack_woT_kernel(const float* __restrict__ wo, unsigned short* __restrict__ out) {
    __shared__ float tile[32][33];
    int n0 = blockIdx.x * 32, k0 = blockIdx.y * 32;
    int tx = threadIdx.x, ty = threadIdx.y;
#pragma unroll
    for (int i = 0; i < 32; i += 8)
        tile[ty + i][tx] = wo[(size_t)(k0 + ty + i) * HIDDEN + n0 + tx];
    __syncthreads();
#pragma unroll
    for (int i = 0; i < 32; i += 8)
        out[(size_t)(n0 + ty + i) * HIDDEN + k0 + tx] = f2bf(tile[tx][ty + i]);
}

// ---------------- GEMM: C(MxN) = A(MxK bf16) @ Bt(NxK bf16)^T, m97-style staging ----------------
template <typename OutT>
__global__ __launch_bounds__(256) void gemm_bt_kernel(const unsigned short* __restrict__ A,
                                                      const unsigned short* __restrict__ Bt,
                                                      OutT* __restrict__ C,
                                                      int M, int N, int K) {
    __shared__ __align__(16) unsigned short sA[128 * 32];  // packed (global_load_lds order)
    __shared__ __align__(16) unsigned short sB[128 * 32];
    const int tid = threadIdx.x;
    const int lane = tid & 63, w = tid >> 6;
    const int quad = lane >> 4, l15 = lane & 15;
    const int wr = w >> 1, wc = w & 1;
    const int m0 = blockIdx.y * 128, n0 = blockIdx.x * 128;

    // lane l covers row (w*16 + (l>>2)) [+64 for 2nd instr], col chunk (l&3)*8
    const unsigned short* gA = A + (size_t)(m0 + w * 16 + (lane >> 2)) * K + (lane & 3) * 8;
    const unsigned short* gB = Bt + (size_t)(n0 + w * 16 + (lane >> 2)) * K + (lane & 3) * 8;
    unsigned short* lA0 = &sA[(w * 16) * 32];
    unsigned short* lA1 = &sA[(64 + w * 16) * 32];
    unsigned short* lB0 = &sB[(w * 16) * 32];
    unsigned short* lB1 = &sB[(64 + w * 16) * 32];
    const size_t rstep = (size_t)64 * K;

    f32x4 acc[4][4];
    const f32x4 z4 = {0.f, 0.f, 0.f, 0.f};
#pragma unroll
    for (int mi = 0; mi < 4; ++mi)
#pragma unroll
        for (int ni = 0; ni < 4; ++ni) acc[mi][ni] = z4;

    for (int kk = 0; kk < K; kk += 32) {
        __syncthreads();
        load_lds_16(gA + kk, lA0);
        load_lds_16(gA + rstep + kk, lA1);
        load_lds_16(gB + kk, lB0);
        load_lds_16(gB + rstep + kk, lB1);
        __syncthreads();
        short8 af[4], bf[4];
#pragma unroll
        for (int i = 0; i < 4; ++i) {
            af[i] = *(const short8*)(&sA[(wr * 64 + i * 16 + l15) * 32 + quad * 8]);
            bf[i] = *(const short8*)(&sB[(wc * 64 + i * 16 + l15) * 32 + quad * 8]);
        }
#pragma unroll
        for (int mi = 0; mi < 4; ++mi)
#pragma unroll
            for (int ni = 0; ni < 4; ++ni)
                acc[mi][ni] = __builtin_amdgcn_mfma_f32_16x16x32_bf16(af[mi], bf[ni], acc[mi][ni], 0, 0, 0);
    }
#pragma unroll
    for (int mi = 0; mi < 4; ++mi)
#pragma unroll
        for (int ni = 0; ni < 4; ++ni)
#pragma unroll
            for (int r = 0; r < 4; ++r) {
                int gr = m0 + wr * 64 + mi * 16 + quad * 4 + r;
                int gc = n0 + wc * 64 + ni * 16 + l15;
                store_out(&C[(size_t)gr * N + gc], acc[mi][ni][r]);
            }
}

// ---------------- RoPE for Q,K: qkv(M x 3072 bf16) -> Q(B,NH,T,128) K(B,NKV,T,128) ----------------
#define QP (MROWS * NHEADS * 64)  // 4194304
#define KP (MROWS * NKV * 64)     // 1048576
__global__ void rope_kernel(const unsigned short* __restrict__ qkv,
                            const float* __restrict__ cosb, const float* __restrict__ sinb,
                            unsigned short* __restrict__ Q, unsigned short* __restrict__ K) {
    int tid = blockIdx.x * 256 + threadIdx.x;
    if (tid < QP) {
        int d = tid & 63;
        int h = (tid >> 6) & 15;
        int row = tid >> 10;
        int t = row & (TT - 1), b = row >> 11;
        float x1 = b2f(qkv[(size_t)row * NQKV + h * 128 + d]);
        float x2 = b2f(qkv[(size_t)row * NQKV + h * 128 + d + 64]);
        float c = cosb[t * 64 + d], s = sinb[t * 64 + d];
        unsigned short* dst = Q + ((size_t)(b * NHEADS + h) * TT + t) * 128 + d;
        dst[0]  = f2bf(x1 * c - x2 * s);
        dst[64] = f2bf(x2 * c + x1 * s);
    } else {
        int p = tid - QP;
        int d = p & 63;
        int kh = (p >> 6) & 3;
        int row = p >> 8;
        int t = row & (TT - 1), b = row >> 11;
        float x1 = b2f(qkv[(size_t)row * NQKV + 2048 + kh * 128 + d]);
        float x2 = b2f(qkv[(size_t)row * NQKV + 2048 + kh * 128 + d + 64]);
        float c = cosb[t * 64 + d], s = sinb[t * 64 + d];
        unsigned short* dst = K + ((size_t)(b * NKV + kh) * TT + t) * 128 + d;
        dst[0]  = f2bf(x1 * c - x2 * s);
        dst[64] = f2bf(x2 * c + x1 * s);
    }
}

// ---------------- V transpose: qkv -> Vt[b][kvh][d][T] ----------------
__global__ void vtrans_kernel(const unsigned short* __restrict__ qkv,
                              unsigned short* __restrict__ Vt) {
    __shared__ unsigned short tile[32][33];
    int t0 = blockIdx.x * 32, d0 = blockIdx.y * 32, bz = blockIdx.z;  // bz = b*NKV+kh
    int b = bz >> 2, kh = bz & 3;
    int tx = threadIdx.x, ty = threadIdx.y;
#pragma unroll
    for (int i = 0; i < 32; i += 8)
        tile[ty + i][tx] = qkv[(size_t)(b * TT + t0 + ty + i) * NQKV + 2560 + kh * 128 + d0 + tx];
    __syncthreads();
#pragma unroll
    for (int i = 0; i < 32; i += 8)
        Vt[((size_t)bz * 128 + d0 + ty + i) * TT + t0 + tx] = tile[tx][ty + i];
}

// ---------------- flash attention: 128 q-rows/block (32/wave), 64-wide kv tiles ----------------
#define PS 68  // sP row stride (64 cols + 4 pad)  -- BUGFIX: was 40, overflowed
__global__ __launch_bounds__(256, 3) void flash_kernel(const unsigned short* __restrict__ Qb,
                                                       const unsigned short* __restrict__ Kb,
                                                       const unsigned short* __restrict__ Vtb,
                                                       unsigned short* __restrict__ Ob) {
    __shared__ __align__(16) unsigned short sK[64 * 136];   // [kv][d], pad
    __shared__ __align__(16) unsigned short sVt[128 * 68];  // [d][kv], pad
    __shared__ __align__(16) unsigned short sP[4][32 * PS]; // per-wave P

    const int tid = threadIdx.x;
    const int w = tid >> 6, lane = tid & 63;
    const int quad = lane >> 4, l15 = lane & 15;
    const int b = blockIdx.z, h = blockIdx.y;
    const int qb = (int)gridDim.x - 1 - (int)blockIdx.x;  // big blocks first
    const int q0 = qb * 128;
    const int kvh = h >> 2;
    const unsigned short* Qh = Qb + (size_t)(b * NHEADS + h) * TT * 128;
    const unsigned short* Kh = Kb + (size_t)(b * NKV + kvh) * TT * 128;
    const unsigned short* Vth = Vtb + (size_t)(b * NKV + kvh) * 128 * TT;

    const int wrow0 = q0 + w * 32;

    short8 aq[2][4];
#pragma unroll
    for (int mi = 0; mi < 2; ++mi)
#pragma unroll
        for (int dk = 0; dk < 4; ++dk)
            aq[mi][dk] = *(const short8*)(Qh + (size_t)(wrow0 + mi * 16 + l15) * 128 + dk * 32 + quad * 8);

    f32x4 accO[2][8], accL[2];
    const f32x4 z4 = {0.f, 0.f, 0.f, 0.f};
#pragma unroll
    for (int mi = 0; mi < 2; ++mi) {
        accL[mi] = z4;
#pragma unroll
        for (int nb = 0; nb < 8; ++nb) accO[mi][nb] = z4;
    }
    float m_i[2][4];
#pragma unroll
    for (int mi = 0; mi < 2; ++mi)
#pragma unroll
        for (int r = 0; r < 4; ++r) m_i[mi][r] = -1e30f;

    const short kone = (short)0x3F80;  // bf16 1.0
    const short8 ones = {kone, kone, kone, kone, kone, kone, kone, kone};
    const float scale = 0.08838834764831845f;  // 1/sqrt(128)
    unsigned short* sPw = &sP[w][0];

    for (int kv0 = 0; kv0 < q0 + 128; kv0 += 64) {
        __syncthreads();
#pragma unroll
        for (int it = 0; it < 4; ++it) {
            int c = tid + 256 * it;
            int krow = c >> 4, kch = c & 15;
            *(uint4*)(&sK[krow * 136 + kch * 8]) =
                *(const uint4*)(Kh + (size_t)(kv0 + krow) * 128 + kch * 8);
            int vd = c >> 3, vch = c & 7;
            *(uint4*)(&sVt[vd * 68 + vch * 8]) =
                *(const uint4*)(Vth + (size_t)vd * TT + kv0 + vch * 8);
        }
        __syncthreads();

        if (kv0 <= wrow0 + 31) {  // wave-uniform
            f32x4 sacc[2][4];
#pragma unroll
            for (int mi = 0; mi < 2; ++mi)
#pragma unroll
                for (int nh = 0; nh < 4; ++nh) sacc[mi][nh] = z4;
#pragma unroll
            for (int nh = 0; nh < 4; ++nh) {
#pragma unroll
                for (int dk = 0; dk < 4; ++dk) {
                    short8 bk = *(const short8*)(&sK[(nh * 16 + l15) * 136 + dk * 32 + quad * 8]);
                    sacc[0][nh] = __builtin_amdgcn_mfma_f32_16x16x32_bf16(aq[0][dk], bk, sacc[0][nh], 0, 0, 0);
                    sacc[1][nh] = __builtin_amdgcn_mfma_f32_16x16x32_bf16(aq[1][dk], bk, sacc[1][nh], 0, 0, 0);
                }
            }
#pragma unroll
            for (int mi = 0; mi < 2; ++mi) {
                const int fr0 = wrow0 + mi * 16;
                const bool needmask = (kv0 + 63) > fr0;
#pragma unroll
                for (int r = 0; r < 4; ++r) {
                    int row = fr0 + quad * 4 + r;
                    float sv[4];
                    float mx = -1e30f;
#pragma unroll
                    for (int nh = 0; nh < 4; ++nh) {
                        float s = sacc[mi][nh][r] * scale;
                        if (needmask) {
                            int col = kv0 + nh * 16 + l15;
                            s = (col <= row) ? s : -1e30f;
                        }
                        sv[nh] = s;
                        mx = fmaxf(mx, s);
                    }
#pragma unroll
                    for (int off = 1; off < 16; off <<= 1) mx = fmaxf(mx, __shfl_xor(mx, off, 64));
                    float mold = m_i[mi][r];
                    float mnew = fmaxf(mold, mx);
                    m_i[mi][r] = mnew;
                    float alpha = __expf(mold - mnew);
                    accL[mi][r] *= alpha;
#pragma unroll
                    for (int nb = 0; nb < 8; ++nb) accO[mi][nb][r] *= alpha;
#pragma unroll
                    for (int nh = 0; nh < 4; ++nh)
                        sPw[(mi * 16 + quad * 4 + r) * PS + nh * 16 + l15] = f2bf(__expf(sv[nh] - mnew));
                }
            }
            __asm__ volatile("s_waitcnt lgkmcnt(0)" ::: "memory");
            short8 ap[2][2];
#pragma unroll
            for (int mi = 0; mi < 2; ++mi) {
#pragma unroll
                for (int kf = 0; kf < 2; ++kf)
                    ap[mi][kf] = *(const short8*)(&sPw[(mi * 16 + l15) * PS + kf * 32 + quad * 8]);
                accL[mi] = __builtin_amdgcn_mfma_f32_16x16x32_bf16(ap[mi][0], ones, accL[mi], 0, 0, 0);
                accL[mi] = __builtin_amdgcn_mfma_f32_16x16x32_bf16(ap[mi][1], ones, accL[mi], 0, 0, 0);
            }
#pragma unroll
            for (int nb = 0; nb < 8; ++nb) {
                short8 bv0 = *(const short8*)(&sVt[(nb * 16 + l15) * 68 + quad * 8]);
                short8 bv1 = *(const short8*)(&sVt[(nb * 16 + l15) * 68 + 32 + quad * 8]);
#pragma unroll
                for (int mi = 0; mi < 2; ++mi) {
                    accO[mi][nb] = __builtin_amdgcn_mfma_f32_16x16x32_bf16(ap[mi][0], bv0, accO[mi][nb], 0, 0, 0);
                    accO[mi][nb] = __builtin_amdgcn_mfma_f32_16x16x32_bf16(ap[mi][1], bv1, accO[mi][nb], 0, 0, 0);
                }
            }
        }
    }
#pragma unroll
    for (int mi = 0; mi < 2; ++mi)
#pragma unroll
        for (int r = 0; r < 4; ++r) {
            float inv = 1.0f / accL[mi][r];
            int row = wrow0 + mi * 16 + quad * 4 + r;
            size_t rowbase = ((size_t)b * TT + row) * (NHEADS * HEAD_DIM) + h * 128;
#pragma unroll
            for (int nb = 0; nb < 8; ++nb)
                Ob[rowbase + nb * 16 + l15] = f2bf(accO[mi][nb][r] * inv);
        }
}

// ---------------- launch ----------------
extern "C" void kernel_launch(void* const* d_in, const int* in_sizes, int n_in,
                              void* d_out, int out_size, void* d_ws, size_t ws_size,
                              hipStream_t stream) {
    const float* x    = (const float*)d_in[0];
    const float* cosb = (const float*)d_in[1];
    const float* sinb = (const float*)d_in[2];
    const float* wq   = (const float*)d_in[3];
    const float* wk   = (const float*)d_in[4];
    const float* wv   = (const float*)d_in[5];
    const float* wo   = (const float*)d_in[6];
    float* out = (float*)d_out;

    char* ws = (char*)d_ws;
    unsigned short* xb    = (unsigned short*)(ws);                       // 16 MB
    unsigned short* wqkvT = (unsigned short*)(ws + (16u << 20));         // 12 MB
    unsigned short* woT   = (unsigned short*)(ws + (28u << 20));         // 8 MB
    unsigned short* qkv   = (unsigned short*)(ws + (36u << 20));         // 24 MB
    unsigned short* Qbuf  = (unsigned short*)(ws + (60u << 20));         // 16 MB
    unsigned short* Kbuf  = (unsigned short*)(ws + (76u << 20));         // 4 MB
    unsigned short* Vt    = (unsigned short*)(ws + (80u << 20));         // 4 MB
    unsigned short* attn  = (unsigned short*)(ws + (84u << 20));         // 16 MB -> 100 MB total

    cast_x_kernel<<<(MROWS * HIDDEN) / 4 / 256, 256, 0, stream>>>(x, xb);
    pack_wqkvT_kernel<<<dim3(NQKV / 32, HIDDEN / 32), dim3(32, 8), 0, stream>>>(wq, wk, wv, wqkvT);
    pack_woT_kernel<<<dim3(HIDDEN / 32, HIDDEN / 32), dim3(32, 8), 0, stream>>>(wo, woT);

    gemm_bt_kernel<unsigned short><<<dim3(NQKV / 128, MROWS / 128), 256, 0, stream>>>(
        xb, wqkvT, qkv, MROWS, NQKV, HIDDEN);

    rope_kernel<<<(QP + KP) / 256, 256, 0, stream>>>(qkv, cosb, sinb, Qbuf, Kbuf);
    vtrans_kernel<<<dim3(TT / 32, HEAD_DIM / 32, BB * NKV), dim3(32, 8), 0, stream>>>(qkv, Vt);

    flash_kernel<<<dim3(TT / 128, NHEADS, BB), 256, 0, stream>>>(Qbuf, Kbuf, Vt, attn);

    gemm_bt_kernel<float><<<dim3(HIDDEN / 128, MROWS / 128), 256, 0, stream>>>(
        attn, woT, out, MROWS, HIDDEN, HIDDEN);
}